// Round 16
// baseline (705.889 us; speedup 1.0000x reference)
//
#include <hip/hip_runtime.h>
#include <hip/hip_bf16.h>

typedef short bf16x8 __attribute__((ext_vector_type(8)));   // 8 bf16 in 4 VGPRs
typedef float f32x4  __attribute__((ext_vector_type(4)));

constexpr int B = 8, T = 10, F = 64, CO = 256;
constexpr long IMGPIX      = 48 * 48;                // 2304
constexpr long STATE_ELEMS = (long)B * IMGPIX * F;   // 1,179,648
constexpr float BN_INVN    = 1.0f / (float)(B * T * IMGPIX);

__device__ __forceinline__ float  b2f(ushort u) { return __uint_as_float(((unsigned)u) << 16); }
__device__ __forceinline__ ushort f2b(float f) {
    unsigned x = __float_as_uint(f);
    return (ushort)((x + 0x7fffu + ((x >> 16) & 1u)) >> 16);   // RNE
}
__device__ __forceinline__ float hsig(float x) { return fminf(fmaxf(0.2f * x + 0.5f, 0.f), 1.f); }
__device__ __forceinline__ float tanh_f(float v) {
    return 1.f - 2.f / (__expf(2.f * v) + 1.f);    // exact at +/-inf, ~1e-6 err
}

union V16 { uint4 u; bf16x8 b; };

// ---------------------------------------------------------------------------
// Fused ConvLSTM step, single-wave / M=96 / Nrep=4 version.
// Grid = 768: (img 0..7) x (row-pair y2 0..23) x (f-quarter q 0..3).
// Block = 64 threads = ONE wave computing 96 px x 16 f-ch x all 4 gates:
// Mrep=6 (2 rows x 3 frags), Nrep=4 (ntile = gate*4+q).  Reads/MFMA = 0.42;
// per-step weight traffic halves vs the 48-px geometry (113 MB vs 226 MB).
// acc[m][g][r] holds gates i,f,c,o of one (pixel,channel) lane-locally ->
// epilogue has ZERO post-staging barriers.
// Staging/layout/SWZ identical to the verified R9 kernel; weight layout is
// the verified interleaved concat swizzle ([ntile][KS][64][8], tap-major
// over CIN_TOT = [x-ch | h-ch]).
// ---------------------------------------------------------------------------
template<int CIN_A, int CPAD, bool SWZ, bool FIRST, bool STATS, bool BNIN, bool OUT>
__global__ __launch_bounds__(64) void convlstm_step(
    const ushort* __restrict__ inA, long strideA,   // per-img stride (elements)
    const ushort* __restrict__ inB,                 // h_prev (B,2304,64) bf16
    const ushort* __restrict__ Wsw,                 // swizzled [ntile][KS][64][8]
    const float*  __restrict__ bias,                // (256)
    float*  __restrict__ cState,                    // (B,2304,64) f32 in place
    ushort* __restrict__ hOut,                      // (B,2304,64) bf16
    ushort* __restrict__ seqOut,                    // STATS only
    float*  __restrict__ stats,                     // [128]
    const float* __restrict__ gamma,
    const float* __restrict__ beta,
    float*  __restrict__ outF)                      // OUT only
{
    constexpr int CIN_TOT = CIN_A + 64;
    constexpr int K   = 9 * CIN_TOT;
    constexpr int KS  = (K + 31) / 32;
    constexpr int KP  = KS * 32;
    constexpr int PATCHB = 4 * 50 * CPAD * 2;        // 2 out rows + halo
    __shared__ __align__(16) unsigned char smem[PATCHB];
    __shared__ float bnsc[64], bnsh[64];

    const int bid = blockIdx.x;
    const int img = bid / 96;
    const int rem = bid % 96;
    const int y2  = rem >> 2;          // row pair 0..23
    const int q   = rem & 3;           // f-quarter 0..3
    const int l   = threadIdx.x;       // 0..63 (one wave)
    const int lm = l & 15, lk8 = (l >> 4) * 8;

    if constexpr (BNIN) {
        const float mean = stats[l] * BN_INVN;
        const float var  = stats[64 + l] * BN_INVN - mean * mean;
        const float sc   = gamma[l] * rsqrtf(var + 1e-3f);
        bnsc[l] = sc;
        bnsh[l] = beta[l] - mean * sc;
        __syncthreads();
    }

    // byte offset into the LDS patch for (patch row r, staged col dc, chan ci0)
    auto lds_off = [&](int r, int dc, int ci0) -> int {
        int byte = ((r * 50 + dc) * CPAD + ci0) * 2;
        if constexpr (SWZ) byte ^= (dc & 7) << 4;
        return byte;
    };

    // ---- stage 4 x 50 x CIN_TOT patch (zero-padded) ----
    const ushort* aBase = inA + (size_t)img * strideA;
    const ushort* bBase = inB + (size_t)img * IMGPIX * 64;
    constexpr int CA8 = CIN_A / 8;
    for (int e = l; e < 4 * 48 * CA8; e += 64) {              // x/seq channels
        const int r = e / (48 * CA8), qq = e % (48 * CA8);
        const int col = qq / CA8, ci0 = (qq % CA8) * 8;
        const int gy = y2 * 2 + r - 1;
        uint4 v = make_uint4(0, 0, 0, 0);
        if (gy >= 0 && gy < 48) {
            v = *(const uint4*)(aBase + ((size_t)gy * 48 + col) * CIN_A + ci0);
            if constexpr (BNIN) {      // BN only on real pixels; padding stays 0
                ushort* u = (ushort*)&v;
#pragma unroll
                for (int j = 0; j < 8; ++j)
                    u[j] = f2b(b2f(u[j]) * bnsc[ci0 + j] + bnsh[ci0 + j]);
            }
        }
        *(uint4*)(smem + lds_off(r, col + 1, ci0)) = v;
    }
    for (int e = l; e < 4 * 48 * 8; e += 64) {                // h channels
        const int r = e / (48 * 8), qq = e % (48 * 8);
        const int col = qq / 8, ci0 = (qq % 8) * 8;
        uint4 v = make_uint4(0, 0, 0, 0);
        if constexpr (!FIRST) {
            const int gy = y2 * 2 + r - 1;
            if (gy >= 0 && gy < 48)
                v = *(const uint4*)(bBase + ((size_t)gy * 48 + col) * 64 + ci0);
        }
        *(uint4*)(smem + lds_off(r, col + 1, CIN_A + ci0)) = v;
    }
    constexpr int CT8 = CIN_TOT / 8;
    for (int e = l; e < 4 * 2 * CT8; e += 64) {               // pad cols 0 and 49
        const int r = e / (2 * CT8), qq = e % (2 * CT8);
        const int dc = (qq / CT8) ? 49 : 0, ci0 = (qq % CT8) * 8;
        *(uint4*)(smem + lds_off(r, dc, ci0)) = make_uint4(0, 0, 0, 0);
    }
    __syncthreads();

    // ---- full-K MFMA loop: Mrep=6, Nrep=4 (gates) ----
    f32x4 acc[6][4] = {};

#pragma unroll
    for (int ks = 0; ks < KS; ++ks) {
        V16 bf[4];
#pragma unroll
        for (int nr = 0; nr < 4; ++nr) {
            const int ntile = nr * 4 + q;
            bf[nr].u = *(const uint4*)(Wsw + ((size_t)((ntile * KS + ks) * 64) + l) * 8);
        }
        const int k   = ks * 32 + lk8;
        const int tap = k / CIN_TOT, ci0 = k % CIN_TOT;
        const int ky  = tap / 3, kx = tap - 3 * (tap / 3);
        V16 af[6];
#pragma unroll
        for (int m = 0; m < 6; ++m) {
            const int sr = (m < 3) ? 0 : 1;          // strip row within pair
            const int fm = (m < 3) ? m : m - 3;      // frag within row
            const int dcc = fm * 16 + lm + kx;
            uint4 v = *(const uint4*)(smem + lds_off(sr + ky, dcc, ci0));
            if (KP > K && ks == KS - 1 && k >= K) v = make_uint4(0, 0, 0, 0);
            af[m].u = v;
        }
#pragma unroll
        for (int m = 0; m < 6; ++m)
#pragma unroll
            for (int nr = 0; nr < 4; ++nr)
                acc[m][nr] = __builtin_amdgcn_mfma_f32_16x16x32_bf16(
                    af[m].b, bf[nr].b, acc[m][nr], 0, 0, 0);
    }

    // ---- lane-local LSTM gate/state update (no barriers) ----
    const float bv_i = bias[      q * 16 + lm];
    const float bv_f = bias[ 64 + q * 16 + lm];
    const float bv_c = bias[128 + q * 16 + lm];
    const float bv_o = bias[192 + q * 16 + lm];

    float s1 = 0.f, s2 = 0.f;
    const size_t rowBase = (size_t)img * IMGPIX + (size_t)y2 * 96;
#pragma unroll
    for (int m = 0; m < 6; ++m)
#pragma unroll
        for (int r = 0; r < 4; ++r) {
            const int p = m * 16 + (l >> 4) * 4 + r;          // 0..95
            const float gi = acc[m][0][r] + bv_i;
            const float gf = acc[m][1][r] + bv_f;
            const float gc = acc[m][2][r] + bv_c;
            const float go = acc[m][3][r] + bv_o;
            const size_t off = (rowBase + p) * 64 + q * 16 + lm;
            const float cold = FIRST ? 0.f : cState[off];
            const float cn = hsig(gf) * cold + hsig(gi) * tanh_f(gc);
            const float hn = hsig(go) * tanh_f(cn);
            cState[off] = cn;
            hOut[off]   = f2b(hn);
            if constexpr (STATS) { seqOut[off] = f2b(hn); s1 += hn; s2 += hn * hn; }
            if constexpr (OUT)   { outF[off] = hn; outF[STATE_ELEMS + off] = cn; }
        }

    if constexpr (STATS) {
        // lanes l, l^16, l^32 hold the same f-channel (lm)
        s1 += __shfl_xor(s1, 16);  s2 += __shfl_xor(s2, 16);
        s1 += __shfl_xor(s1, 32);  s2 += __shfl_xor(s2, 32);
        if (l < 16) {
            atomicAdd(&stats[     q * 16 + lm], s1);
            atomicAdd(&stats[64 + q * 16 + lm], s2);
        }
    }
}

// ---------------------------------------------------------------------------
// One-shot prep: cast x to bf16, build both swizzled concat weights, zero stats.
// Weight layout (verified R7/R9): out[((ntile*KS+ks)*64+l)*8+j] = Wcat[k][n],
// n = ntile*16+(l&15), k = ks*32+((l>>4)&3)*8+j; k-order tap-major,
// ci = [x-ch | h-ch] interleaved per tap.
// ---------------------------------------------------------------------------
__device__ __forceinline__ ushort swz_elem(
    const float* __restrict__ Wx, const float* __restrict__ Wh,
    int CIN_A, int KS, int idx)
{
    const int K = 9 * (CIN_A + 64);
    const int j = idx & 7, lw = (idx >> 3) & 63, rest = idx >> 9;
    const int ks = rest % KS, ntile = rest / KS;
    const int n = ntile * 16 + (lw & 15);
    const int k = ks * 32 + ((lw >> 4) & 3) * 8 + j;
    if (k >= K) return (ushort)0;
    const int CT = CIN_A + 64;
    const int tap = k / CT, ci = k % CT;
    const float v = (ci < CIN_A) ? Wx[((size_t)tap * CIN_A + ci) * CO + n]
                                 : Wh[((size_t)tap * 64 + (ci - CIN_A)) * CO + n];
    return f2b(v);
}

__global__ __launch_bounds__(256) void prep_kernel(
    const float* __restrict__ x,
    const float* __restrict__ Wx1, const float* __restrict__ Wh1,
    const float* __restrict__ Wx2, const float* __restrict__ Wh2,
    ushort* __restrict__ xb, ushort* __restrict__ wc1, ushort* __restrict__ wc2,
    float* __restrict__ stats)
{
    constexpr int N0 = 368640;          // x: 2,949,120 elems / 8
    constexpr int N1 = 16 * 23 * 512;   // 188,416 (K=720, KS=23)
    constexpr int N2 = 16 * 36 * 512;   // 294,912 (K=1152, KS=36)
    const int gid = blockIdx.x * 256 + threadIdx.x;
    if (gid < N0) {
        const float4 a = ((const float4*)x)[(size_t)gid * 2];
        const float4 b = ((const float4*)x)[(size_t)gid * 2 + 1];
        ushort o[8] = { f2b(a.x), f2b(a.y), f2b(a.z), f2b(a.w),
                        f2b(b.x), f2b(b.y), f2b(b.z), f2b(b.w) };
        *(uint4*)(xb + (size_t)gid * 8) = *(const uint4*)o;
    } else if (gid < N0 + N1) {
        wc1[gid - N0] = swz_elem(Wx1, Wh1, 16, 23, gid - N0);
    } else if (gid < N0 + N1 + N2) {
        wc2[gid - N0 - N1] = swz_elem(Wx2, Wh2, 64, 36, gid - N0 - N1);
    } else if (gid < N0 + N1 + N2 + 128) {
        stats[gid - N0 - N1 - N2] = 0.f;
    }
}

// ---------------------------------------------------------------------------
extern "C" void kernel_launch(void* const* d_in, const int* in_sizes, int n_in,
                              void* d_out, int out_size, void* d_ws, size_t ws_size,
                              hipStream_t stream)
{
    const float* x      = (const float*)d_in[0];
    const float* Wx1    = (const float*)d_in[1];
    const float* Wh1    = (const float*)d_in[2];
    const float* b1     = (const float*)d_in[3];
    const float* gamma1 = (const float*)d_in[4];
    const float* beta1  = (const float*)d_in[5];
    const float* Wx2    = (const float*)d_in[6];
    const float* Wh2    = (const float*)d_in[7];
    const float* b2     = (const float*)d_in[8];

    // workspace layout (bytes) -- ~49 MB of the 256 MB ws
    unsigned char* w = (unsigned char*)d_ws;
    ushort* seq1 = (ushort*)w;  w += 23592960;   // (T,B,2304,64) bf16
    ushort* xb   = (ushort*)w;  w += 5898240;    // (B,T,2304,16) bf16
    ushort* wc1  = (ushort*)w;  w += 376832;     // 16*23*512 u16
    ushort* wc2  = (ushort*)w;  w += 589824;     // 16*36*512 u16
    ushort* hb1a = (ushort*)w;  w += 2359296;
    ushort* hb1b = (ushort*)w;  w += 2359296;
    ushort* hb2a = (ushort*)w;  w += 2359296;
    ushort* hb2b = (ushort*)w;  w += 2359296;
    float*  c1   = (float*)w;   w += 4718592;
    float*  c2   = (float*)w;   w += 4718592;
    float*  stats = (float*)w;  w += 512;

    prep_kernel<<<3329, 256, 0, stream>>>(x, Wx1, Wh1, Wx2, Wh2, xb, wc1, wc2, stats);

    const long xStride = (long)T * IMGPIX * 16;
    ushort* hp1[2] = { hb1a, hb1b };

    // ----- layer 1: CIN_A=16, CPAD=88 (non-pow2 stride -> no XOR swizzle) -----
    convlstm_step<16, 88, false, true, true, false, false><<<768, 64, 0, stream>>>(
        xb, xStride, hp1[0], wc1, b1, c1, hp1[1],
        seq1, stats, nullptr, nullptr, nullptr);
    for (int t = 1; t < 9; ++t)
        convlstm_step<16, 88, false, false, true, false, false><<<768, 64, 0, stream>>>(
            xb + (size_t)t * IMGPIX * 16, xStride, hp1[t & 1], wc1, b1, c1, hp1[(t + 1) & 1],
            seq1 + (size_t)t * STATE_ELEMS, stats, nullptr, nullptr, nullptr);
    convlstm_step<16, 88, false, false, true, false, true><<<768, 64, 0, stream>>>(
        xb + (size_t)9 * IMGPIX * 16, xStride, hp1[1], wc1, b1, c1, hp1[0],
        seq1 + (size_t)9 * STATE_ELEMS, stats, nullptr, nullptr, (float*)d_out);

    // ----- layer 2: CIN_A=64, CPAD=128 (pow-2 stride -> bijective XOR swizzle) -----
    ushort* hp2[2] = { hb2a, hb2b };
    convlstm_step<64, 128, true, true, false, true, false><<<768, 64, 0, stream>>>(
        seq1, IMGPIX * 64, hp2[0], wc2, b2, c2, hp2[1],
        nullptr, stats, gamma1, beta1, nullptr);
    for (int t = 1; t < 9; ++t)
        convlstm_step<64, 128, true, false, false, true, false><<<768, 64, 0, stream>>>(
            seq1 + (size_t)t * STATE_ELEMS, IMGPIX * 64, hp2[t & 1], wc2, b2, c2, hp2[(t + 1) & 1],
            nullptr, stats, gamma1, beta1, nullptr);
    convlstm_step<64, 128, true, false, false, true, true><<<768, 64, 0, stream>>>(
        seq1 + (size_t)9 * STATE_ELEMS, IMGPIX * 64, hp2[1], wc2, b2, c2, hp2[0],
        nullptr, stats, gamma1, beta1, (float*)d_out + 2 * STATE_ELEMS);
}

// Round 17
// 399.876 us; speedup vs baseline: 1.7653x; 1.7653x over previous
//
#include <hip/hip_runtime.h>
#include <hip/hip_bf16.h>

typedef short bf16x8 __attribute__((ext_vector_type(8)));   // 8 bf16 in 4 VGPRs
typedef float f32x4  __attribute__((ext_vector_type(4)));

constexpr int B = 8, T = 10, F = 64, CO = 256;
constexpr long IMGPIX      = 48 * 48;                // 2304
constexpr long STATE_ELEMS = (long)B * IMGPIX * F;   // 1,179,648
constexpr float BN_INVN    = 1.0f / (float)(B * T * IMGPIX);

__device__ __forceinline__ float  b2f(ushort u) { return __uint_as_float(((unsigned)u) << 16); }
__device__ __forceinline__ ushort f2b(float f) {
    unsigned x = __float_as_uint(f);
    return (ushort)((x + 0x7fffu + ((x >> 16) & 1u)) >> 16);   // RNE
}
__device__ __forceinline__ float hsig(float x) { return fminf(fmaxf(0.2f * x + 0.5f, 0.f), 1.f); }
__device__ __forceinline__ float tanh_f(float v) {
    return 1.f - 2.f / (__expf(2.f * v) + 1.f);    // exact at +/-inf, ~1e-6 err
}

union V16 { uint4 u; bf16x8 b; };

// ---------------------------------------------------------------------------
// Fused ConvLSTM step, M=96 / 4-wave / 4-way-K-split version.
// Grid = 768: (img 0..7) x (row-pair y2 0..23) x (f-quarter q 0..3).
// Block = 256 threads (4 waves).  Every wave uses ntiles {q,4+q,8+q,12+q}
// (= 4 gates x 16 f-ch) and Mrep=6 over 96 px; wave wid takes ks = 4*ksl+wid.
// Weight bytes/block = 4 ntiles x KS KB for 96 px -> HALF of the 48-px
// geometry's per-pixel weight traffic (device: 221 -> 110 MB/step for L2).
// K-combine: 2-tree in LDS (w0/w2 write gbufA/B in parallel; w1/w3 add in
// parallel; update reads A+B) -> 3 post-stage barriers, no serial phases.
// acc[m][gate][r] is lane-local in gates -> LSTM update needs no transpose.
// ---------------------------------------------------------------------------
template<int CIN_A, int CPAD, bool SWZ, bool FIRST, bool STATS, bool BNIN, bool OUT>
__global__ __launch_bounds__(256, 3) void convlstm_step(
    const ushort* __restrict__ inA, long strideA,   // per-img stride (elements)
    const ushort* __restrict__ inB,                 // h_prev (B,2304,64) bf16
    const ushort* __restrict__ Wsw,                 // swizzled [ntile][KS][64][8]
    const float*  __restrict__ bias,                // (256)
    float*  __restrict__ cState,                    // (B,2304,64) f32 in place
    ushort* __restrict__ hOut,                      // (B,2304,64) bf16
    ushort* __restrict__ seqOut,                    // STATS only
    float*  __restrict__ stats,                     // [128]
    const float* __restrict__ gamma,
    const float* __restrict__ beta,
    float*  __restrict__ outF)                      // OUT only
{
    constexpr int CIN_TOT = CIN_A + 64;
    constexpr int K   = 9 * CIN_TOT;
    constexpr int KS  = (K + 31) / 32;
    constexpr int KP  = KS * 32;
    constexpr int PATCHB = 4 * 50 * CPAD * 2;        // 2 out rows + halo
    constexpr int GBUF1  = 96 * 66 * 4;              // 25,344 (x2 trees = 50,688)
    constexpr int SMEMB  = PATCHB > 2 * GBUF1 ? PATCHB : 2 * GBUF1;
    __shared__ __align__(16) unsigned char smem[SMEMB];
    __shared__ float sred[4][2][16];
    __shared__ float bnsc[64], bnsh[64];

    const int bid = blockIdx.x;
    const int img = bid / 96;
    const int rem = bid % 96;
    const int y2  = rem >> 2;          // row pair 0..23
    const int q   = rem & 3;           // f-quarter 0..3
    const int tid = threadIdx.x, wid = tid >> 6, l = tid & 63;
    const int lm = l & 15, lk8 = (l >> 4) * 8;

    if constexpr (BNIN) {
        if (tid < 64) {
            const float mean = stats[tid] * BN_INVN;
            const float var  = stats[64 + tid] * BN_INVN - mean * mean;
            const float sc   = gamma[tid] * rsqrtf(var + 1e-3f);
            bnsc[tid] = sc;
            bnsh[tid] = beta[tid] - mean * sc;
        }
        __syncthreads();
    }

    // byte offset into the LDS patch for (patch row r, staged col dc, chan ci0)
    auto lds_off = [&](int r, int dc, int ci0) -> int {
        int byte = ((r * 50 + dc) * CPAD + ci0) * 2;
        if constexpr (SWZ) byte ^= (dc & 7) << 4;
        return byte;
    };

    // ---- stage 4 x 50 x CIN_TOT patch (zero-padded) ----
    const ushort* aBase = inA + (size_t)img * strideA;
    const ushort* bBase = inB + (size_t)img * IMGPIX * 64;
    constexpr int CA8 = CIN_A / 8;
    for (int e = tid; e < 4 * 48 * CA8; e += 256) {           // x/seq channels
        const int r = e / (48 * CA8), qq = e % (48 * CA8);
        const int col = qq / CA8, ci0 = (qq % CA8) * 8;
        const int gy = y2 * 2 + r - 1;
        uint4 v = make_uint4(0, 0, 0, 0);
        if (gy >= 0 && gy < 48) {
            v = *(const uint4*)(aBase + ((size_t)gy * 48 + col) * CIN_A + ci0);
            if constexpr (BNIN) {      // BN only on real pixels; padding stays 0
                ushort* u = (ushort*)&v;
#pragma unroll
                for (int j = 0; j < 8; ++j)
                    u[j] = f2b(b2f(u[j]) * bnsc[ci0 + j] + bnsh[ci0 + j]);
            }
        }
        *(uint4*)(smem + lds_off(r, col + 1, ci0)) = v;
    }
    for (int e = tid; e < 4 * 48 * 8; e += 256) {             // h channels
        const int r = e / (48 * 8), qq = e % (48 * 8);
        const int col = qq / 8, ci0 = (qq % 8) * 8;
        uint4 v = make_uint4(0, 0, 0, 0);
        if constexpr (!FIRST) {
            const int gy = y2 * 2 + r - 1;
            if (gy >= 0 && gy < 48)
                v = *(const uint4*)(bBase + ((size_t)gy * 48 + col) * 64 + ci0);
        }
        *(uint4*)(smem + lds_off(r, col + 1, CIN_A + ci0)) = v;
    }
    constexpr int CT8 = CIN_TOT / 8;
    for (int e = tid; e < 4 * 2 * CT8; e += 256) {            // pad cols 0 and 49
        const int r = e / (2 * CT8), qq = e % (2 * CT8);
        const int dc = (qq / CT8) ? 49 : 0, ci0 = (qq % CT8) * 8;
        *(uint4*)(smem + lds_off(r, dc, ci0)) = make_uint4(0, 0, 0, 0);
    }
    __syncthreads();

    // ---- K-loop: ks = 4*ksl + wid (interleaved 4-way split), Mrep=6, Nrep=4 ----
    f32x4 acc[6][4] = {};
    constexpr int KSQ = (KS + 3) / 4;

#pragma unroll
    for (int ksl = 0; ksl < KSQ; ++ksl) {
        const int ks = 4 * ksl + wid;
        if (ks < KS) {
            V16 bf[4];
#pragma unroll
            for (int nr = 0; nr < 4; ++nr) {
                const int ntile = nr * 4 + q;
                bf[nr].u = *(const uint4*)(Wsw + ((size_t)((ntile * KS + ks) * 64) + l) * 8);
            }
            const int k   = ks * 32 + lk8;
            const int tap = k / CIN_TOT, ci0 = k % CIN_TOT;
            const int ky  = tap / 3, kx = tap - 3 * (tap / 3);
            V16 af[6];
#pragma unroll
            for (int m = 0; m < 6; ++m) {
                const int sr = (m < 3) ? 0 : 1;          // strip row within pair
                const int fm = (m < 3) ? m : m - 3;      // frag within row
                const int dcc = fm * 16 + lm + kx;
                uint4 v = *(const uint4*)(smem + lds_off(sr + ky, dcc, ci0));
                if (KP > K && ks == KS - 1 && k >= K) v = make_uint4(0, 0, 0, 0);
                af[m].u = v;
            }
#pragma unroll
            for (int m = 0; m < 6; ++m)
#pragma unroll
                for (int nr = 0; nr < 4; ++nr)
                    acc[m][nr] = __builtin_amdgcn_mfma_f32_16x16x32_bf16(
                        af[m].b, bf[nr].b, acc[m][nr], 0, 0, 0);
        }
    }

    // ---- 2-tree K-combine in LDS (patch region now dead) ----
    __syncthreads();
    float* gbufA = (float*)smem;                 // [96][66]
    float* gbufB = (float*)(smem + GBUF1);       // [96][66]
    float* gb = (wid & 2) ? gbufB : gbufA;

    if ((wid & 1) == 0) {                        // waves 0,2 write in parallel
#pragma unroll
        for (int m = 0; m < 6; ++m)
#pragma unroll
            for (int nr = 0; nr < 4; ++nr)
#pragma unroll
                for (int r = 0; r < 4; ++r) {
                    const int px = m * 16 + (l >> 4) * 4 + r;
                    gb[px * 66 + nr * 16 + lm] = acc[m][nr][r];
                }
    }
    __syncthreads();
    if ((wid & 1) == 1) {                        // waves 1,3 add in parallel
#pragma unroll
        for (int m = 0; m < 6; ++m)
#pragma unroll
            for (int nr = 0; nr < 4; ++nr)
#pragma unroll
                for (int r = 0; r < 4; ++r) {
                    const int px = m * 16 + (l >> 4) * 4 + r;
                    gb[px * 66 + nr * 16 + lm] += acc[m][nr][r];
                }
    }
    __syncthreads();

    // ---- gate / state update: 96 px x 16 f-ch over 256 threads ----
    const int fr = tid & 15;                     // fixed per thread
    const float bv_i = bias[      q * 16 + fr];
    const float bv_f = bias[ 64 + q * 16 + fr];
    const float bv_c = bias[128 + q * 16 + fr];
    const float bv_o = bias[192 + q * 16 + fr];

    float s1 = 0.f, s2 = 0.f;
    const size_t rowBase = (size_t)img * IMGPIX + (size_t)y2 * 96;
#pragma unroll
    for (int it = 0; it < 6; ++it) {
        const int idx = it * 256 + tid;
        const int p = idx >> 4;                  // 0..95
        const float gi = gbufA[p * 66 +      fr] + gbufB[p * 66 +      fr] + bv_i;
        const float gf = gbufA[p * 66 + 16 + fr] + gbufB[p * 66 + 16 + fr] + bv_f;
        const float gc = gbufA[p * 66 + 32 + fr] + gbufB[p * 66 + 32 + fr] + bv_c;
        const float go = gbufA[p * 66 + 48 + fr] + gbufB[p * 66 + 48 + fr] + bv_o;
        const size_t off = (rowBase + p) * 64 + q * 16 + fr;
        const float cold = FIRST ? 0.f : cState[off];
        const float cn = hsig(gf) * cold + hsig(gi) * tanh_f(gc);
        const float hn = hsig(go) * tanh_f(cn);
        cState[off] = cn;
        hOut[off]   = f2b(hn);
        if constexpr (STATS) { seqOut[off] = f2b(hn); s1 += hn; s2 += hn * hn; }
        if constexpr (OUT)   { outF[off] = hn; outF[STATE_ELEMS + off] = cn; }
    }

    if constexpr (STATS) {
        // lanes l, l^16, l^32 hold the same f-channel (tid&15)
        s1 += __shfl_xor(s1, 16);  s2 += __shfl_xor(s2, 16);
        s1 += __shfl_xor(s1, 32);  s2 += __shfl_xor(s2, 32);
        if (l < 16) { sred[wid][0][l] = s1; sred[wid][1][l] = s2; }
        __syncthreads();
        if (tid < 32) {
            const int kind = tid >> 4, fc = tid & 15;
            const float v = sred[0][kind][fc] + sred[1][kind][fc]
                          + sred[2][kind][fc] + sred[3][kind][fc];
            atomicAdd(&stats[kind * 64 + q * 16 + fc], v);
        }
    }
}

// ---------------------------------------------------------------------------
// One-shot prep: cast x to bf16, build both swizzled concat weights, zero stats.
// Weight layout (verified R7/R9/R16): out[((ntile*KS+ks)*64+l)*8+j] = Wcat[k][n],
// n = ntile*16+(l&15), k = ks*32+((l>>4)&3)*8+j; k-order tap-major,
// ci = [x-ch | h-ch] interleaved per tap.
// ---------------------------------------------------------------------------
__device__ __forceinline__ ushort swz_elem(
    const float* __restrict__ Wx, const float* __restrict__ Wh,
    int CIN_A, int KS, int idx)
{
    const int K = 9 * (CIN_A + 64);
    const int j = idx & 7, lw = (idx >> 3) & 63, rest = idx >> 9;
    const int ks = rest % KS, ntile = rest / KS;
    const int n = ntile * 16 + (lw & 15);
    const int k = ks * 32 + ((lw >> 4) & 3) * 8 + j;
    if (k >= K) return (ushort)0;
    const int CT = CIN_A + 64;
    const int tap = k / CT, ci = k % CT;
    const float v = (ci < CIN_A) ? Wx[((size_t)tap * CIN_A + ci) * CO + n]
                                 : Wh[((size_t)tap * 64 + (ci - CIN_A)) * CO + n];
    return f2b(v);
}

__global__ __launch_bounds__(256) void prep_kernel(
    const float* __restrict__ x,
    const float* __restrict__ Wx1, const float* __restrict__ Wh1,
    const float* __restrict__ Wx2, const float* __restrict__ Wh2,
    ushort* __restrict__ xb, ushort* __restrict__ wc1, ushort* __restrict__ wc2,
    float* __restrict__ stats)
{
    constexpr int N0 = 368640;          // x: 2,949,120 elems / 8
    constexpr int N1 = 16 * 23 * 512;   // 188,416 (K=720, KS=23)
    constexpr int N2 = 16 * 36 * 512;   // 294,912 (K=1152, KS=36)
    const int gid = blockIdx.x * 256 + threadIdx.x;
    if (gid < N0) {
        const float4 a = ((const float4*)x)[(size_t)gid * 2];
        const float4 b = ((const float4*)x)[(size_t)gid * 2 + 1];
        ushort o[8] = { f2b(a.x), f2b(a.y), f2b(a.z), f2b(a.w),
                        f2b(b.x), f2b(b.y), f2b(b.z), f2b(b.w) };
        *(uint4*)(xb + (size_t)gid * 8) = *(const uint4*)o;
    } else if (gid < N0 + N1) {
        wc1[gid - N0] = swz_elem(Wx1, Wh1, 16, 23, gid - N0);
    } else if (gid < N0 + N1 + N2) {
        wc2[gid - N0 - N1] = swz_elem(Wx2, Wh2, 64, 36, gid - N0 - N1);
    } else if (gid < N0 + N1 + N2 + 128) {
        stats[gid - N0 - N1 - N2] = 0.f;
    }
}

// ---------------------------------------------------------------------------
extern "C" void kernel_launch(void* const* d_in, const int* in_sizes, int n_in,
                              void* d_out, int out_size, void* d_ws, size_t ws_size,
                              hipStream_t stream)
{
    const float* x      = (const float*)d_in[0];
    const float* Wx1    = (const float*)d_in[1];
    const float* Wh1    = (const float*)d_in[2];
    const float* b1     = (const float*)d_in[3];
    const float* gamma1 = (const float*)d_in[4];
    const float* beta1  = (const float*)d_in[5];
    const float* Wx2    = (const float*)d_in[6];
    const float* Wh2    = (const float*)d_in[7];
    const float* b2     = (const float*)d_in[8];

    // workspace layout (bytes) -- ~49 MB of the 256 MB ws
    unsigned char* w = (unsigned char*)d_ws;
    ushort* seq1 = (ushort*)w;  w += 23592960;   // (T,B,2304,64) bf16
    ushort* xb   = (ushort*)w;  w += 5898240;    // (B,T,2304,16) bf16
    ushort* wc1  = (ushort*)w;  w += 376832;     // 16*23*512 u16
    ushort* wc2  = (ushort*)w;  w += 589824;     // 16*36*512 u16
    ushort* hb1a = (ushort*)w;  w += 2359296;
    ushort* hb1b = (ushort*)w;  w += 2359296;
    ushort* hb2a = (ushort*)w;  w += 2359296;
    ushort* hb2b = (ushort*)w;  w += 2359296;
    float*  c1   = (float*)w;   w += 4718592;
    float*  c2   = (float*)w;   w += 4718592;
    float*  stats = (float*)w;  w += 512;

    prep_kernel<<<3329, 256, 0, stream>>>(x, Wx1, Wh1, Wx2, Wh2, xb, wc1, wc2, stats);

    const long xStride = (long)T * IMGPIX * 16;
    ushort* hp1[2] = { hb1a, hb1b };

    // ----- layer 1: CIN_A=16, CPAD=88 (non-pow2 stride -> no XOR swizzle) -----
    convlstm_step<16, 88, false, true, true, false, false><<<768, 256, 0, stream>>>(
        xb, xStride, hp1[0], wc1, b1, c1, hp1[1],
        seq1, stats, nullptr, nullptr, nullptr);
    for (int t = 1; t < 9; ++t)
        convlstm_step<16, 88, false, false, true, false, false><<<768, 256, 0, stream>>>(
            xb + (size_t)t * IMGPIX * 16, xStride, hp1[t & 1], wc1, b1, c1, hp1[(t + 1) & 1],
            seq1 + (size_t)t * STATE_ELEMS, stats, nullptr, nullptr, nullptr);
    convlstm_step<16, 88, false, false, true, false, true><<<768, 256, 0, stream>>>(
        xb + (size_t)9 * IMGPIX * 16, xStride, hp1[1], wc1, b1, c1, hp1[0],
        seq1 + (size_t)9 * STATE_ELEMS, stats, nullptr, nullptr, (float*)d_out);

    // ----- layer 2: CIN_A=64, CPAD=128 (pow-2 stride -> bijective XOR swizzle) -----
    ushort* hp2[2] = { hb2a, hb2b };
    convlstm_step<64, 128, true, true, false, true, false><<<768, 256, 0, stream>>>(
        seq1, IMGPIX * 64, hp2[0], wc2, b2, c2, hp2[1],
        nullptr, stats, gamma1, beta1, nullptr);
    for (int t = 1; t < 9; ++t)
        convlstm_step<64, 128, true, false, false, true, false><<<768, 256, 0, stream>>>(
            seq1 + (size_t)t * STATE_ELEMS, IMGPIX * 64, hp2[t & 1], wc2, b2, c2, hp2[(t + 1) & 1],
            nullptr, stats, gamma1, beta1, nullptr);
    convlstm_step<64, 128, true, false, false, true, true><<<768, 256, 0, stream>>>(
        seq1 + (size_t)9 * STATE_ELEMS, IMGPIX * 64, hp2[1], wc2, b2, c2, hp2[0],
        nullptr, stats, gamma1, beta1, (float*)d_out + 2 * STATE_ELEMS);
}

// Round 18
// 340.235 us; speedup vs baseline: 2.0747x; 1.1753x over previous
//
#include <hip/hip_runtime.h>
#include <hip/hip_bf16.h>

typedef short bf16x8 __attribute__((ext_vector_type(8)));   // 8 bf16 in 4 VGPRs
typedef float f32x4  __attribute__((ext_vector_type(4)));

constexpr int B = 8, T = 10, F = 64, CO = 256;
constexpr long IMGPIX      = 48 * 48;                // 2304
constexpr long STATE_ELEMS = (long)B * IMGPIX * F;   // 1,179,648
constexpr float BN_INVN    = 1.0f / (float)(B * T * IMGPIX);

__device__ __forceinline__ float  b2f(ushort u) { return __uint_as_float(((unsigned)u) << 16); }
__device__ __forceinline__ ushort f2b(float f) {
    unsigned x = __float_as_uint(f);
    return (ushort)((x + 0x7fffu + ((x >> 16) & 1u)) >> 16);   // RNE
}
__device__ __forceinline__ float hsig(float x) { return fminf(fmaxf(0.2f * x + 0.5f, 0.f), 1.f); }
__device__ __forceinline__ float tanh_f(float v) {
    return 1.f - 2.f / (__expf(2.f * v) + 1.f);    // exact at +/-inf, ~1e-6 err
}

union V16 { uint4 u; bf16x8 b; };

// ---------------------------------------------------------------------------
// Fused ConvLSTM step, M=96 / 4-wave / 4-way-K-split (R17-verified math).
// R18 change: XCD-locality block decode.  img = bid & 7, slot = bid >> 3 --
// with round-robin dispatch (XCD = bid % 8), ALL 96 blocks of an image stay
// on ONE XCD (32 CUs x 3 blocks, balanced) for all 20 steps, so h/c/halo
// reads hit that XCD's L2 instead of crossing to L3/HBM every step.
// Pure perf heuristic: wrong mapping only costs speed, never correctness.
// ---------------------------------------------------------------------------
template<int CIN_A, int CPAD, bool SWZ, bool FIRST, bool STATS, bool BNIN, bool OUT>
__global__ __launch_bounds__(256, 3) void convlstm_step(
    const ushort* __restrict__ inA, long strideA,   // per-img stride (elements)
    const ushort* __restrict__ inB,                 // h_prev (B,2304,64) bf16
    const ushort* __restrict__ Wsw,                 // swizzled [ntile][KS][64][8]
    const float*  __restrict__ bias,                // (256)
    float*  __restrict__ cState,                    // (B,2304,64) f32 in place
    ushort* __restrict__ hOut,                      // (B,2304,64) bf16
    ushort* __restrict__ seqOut,                    // STATS only
    float*  __restrict__ stats,                     // [128]
    const float* __restrict__ gamma,
    const float* __restrict__ beta,
    float*  __restrict__ outF)                      // OUT only
{
    constexpr int CIN_TOT = CIN_A + 64;
    constexpr int K   = 9 * CIN_TOT;
    constexpr int KS  = (K + 31) / 32;
    constexpr int KP  = KS * 32;
    constexpr int PATCHB = 4 * 50 * CPAD * 2;        // 2 out rows + halo
    constexpr int GBUF1  = 96 * 66 * 4;              // 25,344 (x2 trees = 50,688)
    constexpr int SMEMB  = PATCHB > 2 * GBUF1 ? PATCHB : 2 * GBUF1;
    __shared__ __align__(16) unsigned char smem[SMEMB];
    __shared__ float sred[4][2][16];
    __shared__ float bnsc[64], bnsh[64];

    const int bid  = blockIdx.x;
    const int img  = bid & 7;          // == XCD id under round-robin dispatch
    const int slot = bid >> 3;         // 0..95 within the image
    const int y2   = slot >> 2;        // row pair 0..23
    const int q    = slot & 3;         // f-quarter 0..3
    const int tid = threadIdx.x, wid = tid >> 6, l = tid & 63;
    const int lm = l & 15, lk8 = (l >> 4) * 8;

    if constexpr (BNIN) {
        if (tid < 64) {
            const float mean = stats[tid] * BN_INVN;
            const float var  = stats[64 + tid] * BN_INVN - mean * mean;
            const float sc   = gamma[tid] * rsqrtf(var + 1e-3f);
            bnsc[tid] = sc;
            bnsh[tid] = beta[tid] - mean * sc;
        }
        __syncthreads();
    }

    // byte offset into the LDS patch for (patch row r, staged col dc, chan ci0)
    auto lds_off = [&](int r, int dc, int ci0) -> int {
        int byte = ((r * 50 + dc) * CPAD + ci0) * 2;
        if constexpr (SWZ) byte ^= (dc & 7) << 4;
        return byte;
    };

    // ---- stage 4 x 50 x CIN_TOT patch (zero-padded) ----
    const ushort* aBase = inA + (size_t)img * strideA;
    const ushort* bBase = inB + (size_t)img * IMGPIX * 64;
    constexpr int CA8 = CIN_A / 8;
    for (int e = tid; e < 4 * 48 * CA8; e += 256) {           // x/seq channels
        const int r = e / (48 * CA8), qq = e % (48 * CA8);
        const int col = qq / CA8, ci0 = (qq % CA8) * 8;
        const int gy = y2 * 2 + r - 1;
        uint4 v = make_uint4(0, 0, 0, 0);
        if (gy >= 0 && gy < 48) {
            v = *(const uint4*)(aBase + ((size_t)gy * 48 + col) * CIN_A + ci0);
            if constexpr (BNIN) {      // BN only on real pixels; padding stays 0
                ushort* u = (ushort*)&v;
#pragma unroll
                for (int j = 0; j < 8; ++j)
                    u[j] = f2b(b2f(u[j]) * bnsc[ci0 + j] + bnsh[ci0 + j]);
            }
        }
        *(uint4*)(smem + lds_off(r, col + 1, ci0)) = v;
    }
    for (int e = tid; e < 4 * 48 * 8; e += 256) {             // h channels
        const int r = e / (48 * 8), qq = e % (48 * 8);
        const int col = qq / 8, ci0 = (qq % 8) * 8;
        uint4 v = make_uint4(0, 0, 0, 0);
        if constexpr (!FIRST) {
            const int gy = y2 * 2 + r - 1;
            if (gy >= 0 && gy < 48)
                v = *(const uint4*)(bBase + ((size_t)gy * 48 + col) * 64 + ci0);
        }
        *(uint4*)(smem + lds_off(r, col + 1, CIN_A + ci0)) = v;
    }
    constexpr int CT8 = CIN_TOT / 8;
    for (int e = tid; e < 4 * 2 * CT8; e += 256) {            // pad cols 0 and 49
        const int r = e / (2 * CT8), qq = e % (2 * CT8);
        const int dc = (qq / CT8) ? 49 : 0, ci0 = (qq % CT8) * 8;
        *(uint4*)(smem + lds_off(r, dc, ci0)) = make_uint4(0, 0, 0, 0);
    }
    __syncthreads();

    // ---- K-loop: ks = 4*ksl + wid (interleaved 4-way split), Mrep=6, Nrep=4 ----
    f32x4 acc[6][4] = {};
    constexpr int KSQ = (KS + 3) / 4;

#pragma unroll
    for (int ksl = 0; ksl < KSQ; ++ksl) {
        const int ks = 4 * ksl + wid;
        if (ks < KS) {
            V16 bf[4];
#pragma unroll
            for (int nr = 0; nr < 4; ++nr) {
                const int ntile = nr * 4 + q;
                bf[nr].u = *(const uint4*)(Wsw + ((size_t)((ntile * KS + ks) * 64) + l) * 8);
            }
            const int k   = ks * 32 + lk8;
            const int tap = k / CIN_TOT, ci0 = k % CIN_TOT;
            const int ky  = tap / 3, kx = tap - 3 * (tap / 3);
            V16 af[6];
#pragma unroll
            for (int m = 0; m < 6; ++m) {
                const int sr = (m < 3) ? 0 : 1;          // strip row within pair
                const int fm = (m < 3) ? m : m - 3;      // frag within row
                const int dcc = fm * 16 + lm + kx;
                uint4 v = *(const uint4*)(smem + lds_off(sr + ky, dcc, ci0));
                if (KP > K && ks == KS - 1 && k >= K) v = make_uint4(0, 0, 0, 0);
                af[m].u = v;
            }
#pragma unroll
            for (int m = 0; m < 6; ++m)
#pragma unroll
                for (int nr = 0; nr < 4; ++nr)
                    acc[m][nr] = __builtin_amdgcn_mfma_f32_16x16x32_bf16(
                        af[m].b, bf[nr].b, acc[m][nr], 0, 0, 0);
        }
    }

    // ---- 2-tree K-combine in LDS (patch region now dead) ----
    __syncthreads();
    float* gbufA = (float*)smem;                 // [96][66]
    float* gbufB = (float*)(smem + GBUF1);       // [96][66]
    float* gb = (wid & 2) ? gbufB : gbufA;

    if ((wid & 1) == 0) {                        // waves 0,2 write in parallel
#pragma unroll
        for (int m = 0; m < 6; ++m)
#pragma unroll
            for (int nr = 0; nr < 4; ++nr)
#pragma unroll
                for (int r = 0; r < 4; ++r) {
                    const int px = m * 16 + (l >> 4) * 4 + r;
                    gb[px * 66 + nr * 16 + lm] = acc[m][nr][r];
                }
    }
    __syncthreads();
    if ((wid & 1) == 1) {                        // waves 1,3 add in parallel
#pragma unroll
        for (int m = 0; m < 6; ++m)
#pragma unroll
            for (int nr = 0; nr < 4; ++nr)
#pragma unroll
                for (int r = 0; r < 4; ++r) {
                    const int px = m * 16 + (l >> 4) * 4 + r;
                    gb[px * 66 + nr * 16 + lm] += acc[m][nr][r];
                }
    }
    __syncthreads();

    // ---- gate / state update: 96 px x 16 f-ch over 256 threads ----
    const int fr = tid & 15;                     // fixed per thread
    const float bv_i = bias[      q * 16 + fr];
    const float bv_f = bias[ 64 + q * 16 + fr];
    const float bv_c = bias[128 + q * 16 + fr];
    const float bv_o = bias[192 + q * 16 + fr];

    float s1 = 0.f, s2 = 0.f;
    const size_t rowBase = (size_t)img * IMGPIX + (size_t)y2 * 96;
#pragma unroll
    for (int it = 0; it < 6; ++it) {
        const int idx = it * 256 + tid;
        const int p = idx >> 4;                  // 0..95
        const float gi = gbufA[p * 66 +      fr] + gbufB[p * 66 +      fr] + bv_i;
        const float gf = gbufA[p * 66 + 16 + fr] + gbufB[p * 66 + 16 + fr] + bv_f;
        const float gc = gbufA[p * 66 + 32 + fr] + gbufB[p * 66 + 32 + fr] + bv_c;
        const float go = gbufA[p * 66 + 48 + fr] + gbufB[p * 66 + 48 + fr] + bv_o;
        const size_t off = (rowBase + p) * 64 + q * 16 + fr;
        const float cold = FIRST ? 0.f : cState[off];
        const float cn = hsig(gf) * cold + hsig(gi) * tanh_f(gc);
        const float hn = hsig(go) * tanh_f(cn);
        cState[off] = cn;
        hOut[off]   = f2b(hn);
        if constexpr (STATS) { seqOut[off] = f2b(hn); s1 += hn; s2 += hn * hn; }
        if constexpr (OUT)   { outF[off] = hn; outF[STATE_ELEMS + off] = cn; }
    }

    if constexpr (STATS) {
        // lanes l, l^16, l^32 hold the same f-channel (tid&15)
        s1 += __shfl_xor(s1, 16);  s2 += __shfl_xor(s2, 16);
        s1 += __shfl_xor(s1, 32);  s2 += __shfl_xor(s2, 32);
        if (l < 16) { sred[wid][0][l] = s1; sred[wid][1][l] = s2; }
        __syncthreads();
        if (tid < 32) {
            const int kind = tid >> 4, fc = tid & 15;
            const float v = sred[0][kind][fc] + sred[1][kind][fc]
                          + sred[2][kind][fc] + sred[3][kind][fc];
            atomicAdd(&stats[kind * 64 + q * 16 + fc], v);
        }
    }
}

// ---------------------------------------------------------------------------
// One-shot prep: cast x to bf16, build both swizzled concat weights, zero stats.
// Weight layout (verified R7/R9/R16/R17): out[((ntile*KS+ks)*64+l)*8+j] =
// Wcat[k][n], n = ntile*16+(l&15), k = ks*32+((l>>4)&3)*8+j; k-order
// tap-major, ci = [x-ch | h-ch] interleaved per tap.
// ---------------------------------------------------------------------------
__device__ __forceinline__ ushort swz_elem(
    const float* __restrict__ Wx, const float* __restrict__ Wh,
    int CIN_A, int KS, int idx)
{
    const int K = 9 * (CIN_A + 64);
    const int j = idx & 7, lw = (idx >> 3) & 63, rest = idx >> 9;
    const int ks = rest % KS, ntile = rest / KS;
    const int n = ntile * 16 + (lw & 15);
    const int k = ks * 32 + ((lw >> 4) & 3) * 8 + j;
    if (k >= K) return (ushort)0;
    const int CT = CIN_A + 64;
    const int tap = k / CT, ci = k % CT;
    const float v = (ci < CIN_A) ? Wx[((size_t)tap * CIN_A + ci) * CO + n]
                                 : Wh[((size_t)tap * 64 + (ci - CIN_A)) * CO + n];
    return f2b(v);
}

__global__ __launch_bounds__(256) void prep_kernel(
    const float* __restrict__ x,
    const float* __restrict__ Wx1, const float* __restrict__ Wh1,
    const float* __restrict__ Wx2, const float* __restrict__ Wh2,
    ushort* __restrict__ xb, ushort* __restrict__ wc1, ushort* __restrict__ wc2,
    float* __restrict__ stats)
{
    constexpr int N0 = 368640;          // x: 2,949,120 elems / 8
    constexpr int N1 = 16 * 23 * 512;   // 188,416 (K=720, KS=23)
    constexpr int N2 = 16 * 36 * 512;   // 294,912 (K=1152, KS=36)
    const int gid = blockIdx.x * 256 + threadIdx.x;
    if (gid < N0) {
        const float4 a = ((const float4*)x)[(size_t)gid * 2];
        const float4 b = ((const float4*)x)[(size_t)gid * 2 + 1];
        ushort o[8] = { f2b(a.x), f2b(a.y), f2b(a.z), f2b(a.w),
                        f2b(b.x), f2b(b.y), f2b(b.z), f2b(b.w) };
        *(uint4*)(xb + (size_t)gid * 8) = *(const uint4*)o;
    } else if (gid < N0 + N1) {
        wc1[gid - N0] = swz_elem(Wx1, Wh1, 16, 23, gid - N0);
    } else if (gid < N0 + N1 + N2) {
        wc2[gid - N0 - N1] = swz_elem(Wx2, Wh2, 64, 36, gid - N0 - N1);
    } else if (gid < N0 + N1 + N2 + 128) {
        stats[gid - N0 - N1 - N2] = 0.f;
    }
}

// ---------------------------------------------------------------------------
extern "C" void kernel_launch(void* const* d_in, const int* in_sizes, int n_in,
                              void* d_out, int out_size, void* d_ws, size_t ws_size,
                              hipStream_t stream)
{
    const float* x      = (const float*)d_in[0];
    const float* Wx1    = (const float*)d_in[1];
    const float* Wh1    = (const float*)d_in[2];
    const float* b1     = (const float*)d_in[3];
    const float* gamma1 = (const float*)d_in[4];
    const float* beta1  = (const float*)d_in[5];
    const float* Wx2    = (const float*)d_in[6];
    const float* Wh2    = (const float*)d_in[7];
    const float* b2     = (const float*)d_in[8];

    // workspace layout (bytes) -- ~49 MB of the 256 MB ws
    unsigned char* w = (unsigned char*)d_ws;
    ushort* seq1 = (ushort*)w;  w += 23592960;   // (T,B,2304,64) bf16
    ushort* xb   = (ushort*)w;  w += 5898240;    // (B,T,2304,16) bf16
    ushort* wc1  = (ushort*)w;  w += 376832;     // 16*23*512 u16
    ushort* wc2  = (ushort*)w;  w += 589824;     // 16*36*512 u16
    ushort* hb1a = (ushort*)w;  w += 2359296;
    ushort* hb1b = (ushort*)w;  w += 2359296;
    ushort* hb2a = (ushort*)w;  w += 2359296;
    ushort* hb2b = (ushort*)w;  w += 2359296;
    float*  c1   = (float*)w;   w += 4718592;
    float*  c2   = (float*)w;   w += 4718592;
    float*  stats = (float*)w;  w += 512;

    prep_kernel<<<3329, 256, 0, stream>>>(x, Wx1, Wh1, Wx2, Wh2, xb, wc1, wc2, stats);

    const long xStride = (long)T * IMGPIX * 16;
    ushort* hp1[2] = { hb1a, hb1b };

    // ----- layer 1: CIN_A=16, CPAD=88 (non-pow2 stride -> no XOR swizzle) -----
    convlstm_step<16, 88, false, true, true, false, false><<<768, 256, 0, stream>>>(
        xb, xStride, hp1[0], wc1, b1, c1, hp1[1],
        seq1, stats, nullptr, nullptr, nullptr);
    for (int t = 1; t < 9; ++t)
        convlstm_step<16, 88, false, false, true, false, false><<<768, 256, 0, stream>>>(
            xb + (size_t)t * IMGPIX * 16, xStride, hp1[t & 1], wc1, b1, c1, hp1[(t + 1) & 1],
            seq1 + (size_t)t * STATE_ELEMS, stats, nullptr, nullptr, nullptr);
    convlstm_step<16, 88, false, false, true, false, true><<<768, 256, 0, stream>>>(
        xb + (size_t)9 * IMGPIX * 16, xStride, hp1[1], wc1, b1, c1, hp1[0],
        seq1 + (size_t)9 * STATE_ELEMS, stats, nullptr, nullptr, (float*)d_out);

    // ----- layer 2: CIN_A=64, CPAD=128 (pow-2 stride -> bijective XOR swizzle) -----
    ushort* hp2[2] = { hb2a, hb2b };
    convlstm_step<64, 128, true, true, false, true, false><<<768, 256, 0, stream>>>(
        seq1, IMGPIX * 64, hp2[0], wc2, b2, c2, hp2[1],
        nullptr, stats, gamma1, beta1, nullptr);
    for (int t = 1; t < 9; ++t)
        convlstm_step<64, 128, true, false, false, true, false><<<768, 256, 0, stream>>>(
            seq1 + (size_t)t * STATE_ELEMS, IMGPIX * 64, hp2[t & 1], wc2, b2, c2, hp2[(t + 1) & 1],
            nullptr, stats, gamma1, beta1, nullptr);
    convlstm_step<64, 128, true, false, false, true, true><<<768, 256, 0, stream>>>(
        seq1 + (size_t)9 * STATE_ELEMS, IMGPIX * 64, hp2[1], wc2, b2, c2, hp2[0],
        nullptr, stats, gamma1, beta1, (float*)d_out + 2 * STATE_ELEMS);
}